// Round 11
// baseline (389.451 us; speedup 1.0000x reference)
//
#include <hip/hip_runtime.h>
#include <hip/hip_bf16.h>
#include <math.h>

// Problem constants
#define NE    1024   // n_embd
#define DI    2048   // d_inner
#define LSEQ  2048   // L
#define NB    2      // batch
#define DS    16     // d_state
#define DTR   64     // dt_rank
#define XDW   96     // dt_rank + 2*d_state

#define CCH   64           // number of time chunks for the scan
#define TCH   (LSEQ/CCH)   // 32 timesteps per chunk

#define SKX   8            // split-K factor for x_proj
#define XPROJ_PART (4096*96)

typedef __attribute__((ext_vector_type(8))) short short8;   // 8 x bf16 (4 VGPRs)
typedef __attribute__((ext_vector_type(4))) float floatx4;  // MFMA accumulator

__device__ __forceinline__ float softplusf(float x) {
    return (x > 20.f) ? x : log1pf(expf(x));
}
__device__ __forceinline__ float softplus_fast(float x) {
    return (x > 20.f) ? x : __logf(1.f + __expf(x));
}
__device__ __forceinline__ float siluf(float x) {
    return x / (1.f + __expf(-x));
}

__device__ __forceinline__ void gld16(const void* g, void* l) {
    __builtin_amdgcn_global_load_lds(
        (const __attribute__((address_space(1))) unsigned int*)g,
        (__attribute__((address_space(3))) unsigned int*)l, 16, 0, 0);
}

// ---------------- prep: LayerNorm (blocks 0..4095) + 4x f2bf (rest) ---------
#define F2BF_N1 (4096*1024/4)          // in_w groups
#define F2BF_N2 (2048*1024/4)          // out_w groups
#define F2BF_N3 (96*2048/4)            // xproj_w groups
#define F2BF_N4 (2048*64/4)            // dtproj_w groups
#define LN_BLOCKS 4096
#define F2BF_BLOCKS ((F2BF_N1 + F2BF_N2 + F2BF_N3 + F2BF_N4) / 256)

__global__ __launch_bounds__(256) void prep_kernel(
    const float* __restrict__ x, const float* __restrict__ g,
    const float* __restrict__ b, __hip_bfloat16* __restrict__ xn,
    const float* __restrict__ s1, ushort4* __restrict__ d1,
    const float* __restrict__ s2, ushort4* __restrict__ d2,
    const float* __restrict__ s3, ushort4* __restrict__ d3,
    const float* __restrict__ s4, ushort4* __restrict__ d4)
{
    int tid = threadIdx.x;
    if (blockIdx.x >= LN_BLOCKS) {
        int i = (blockIdx.x - LN_BLOCKS) * 256 + tid;
        const float* src; ushort4* dst; int j;
        if (i < F2BF_N1)                           { src = s1; dst = d1; j = i; }
        else if (i < F2BF_N1 + F2BF_N2)            { src = s2; dst = d2; j = i - F2BF_N1; }
        else if (i < F2BF_N1 + F2BF_N2 + F2BF_N3)  { src = s3; dst = d3; j = i - F2BF_N1 - F2BF_N2; }
        else                                       { src = s4; dst = d4; j = i - F2BF_N1 - F2BF_N2 - F2BF_N3; }
        float4 v = ((const float4*)src)[j];
        union { __hip_bfloat16 h[4]; ushort4 u; } cv;
        cv.h[0] = __float2bfloat16(v.x);
        cv.h[1] = __float2bfloat16(v.y);
        cv.h[2] = __float2bfloat16(v.z);
        cv.h[3] = __float2bfloat16(v.w);
        dst[j] = cv.u;
        return;
    }
    int row = blockIdx.x;
    const float4* xr = (const float4*)(x + (size_t)row * NE);
    float4 v = xr[tid];                       // 256 threads * 4 = 1024
    float s  = v.x + v.y + v.z + v.w;
    float sq = v.x*v.x + v.y*v.y + v.z*v.z + v.w*v.w;
    #pragma unroll
    for (int off = 32; off > 0; off >>= 1) {  // wave64 reduce
        s  += __shfl_down(s, off);
        sq += __shfl_down(sq, off);
    }
    __shared__ float ss[4], ssq[4];
    __shared__ float smu, srstd;
    int wv = tid >> 6, lane = tid & 63;
    if (lane == 0) { ss[wv] = s; ssq[wv] = sq; }
    __syncthreads();
    if (tid == 0) {
        float a = ss[0] + ss[1] + ss[2] + ss[3];
        float q = ssq[0] + ssq[1] + ssq[2] + ssq[3];
        float mu  = a * (1.f / NE);
        float var = q * (1.f / NE) - mu * mu;   // biased var, matches jnp.var
        smu = mu; srstd = rsqrtf(var + 1e-5f);
    }
    __syncthreads();
    float mu = smu, rstd = srstd;
    float4 gv = ((const float4*)g)[tid];
    float4 bv = ((const float4*)b)[tid];
    union { __hip_bfloat16 h[4]; ushort4 u; } cv;
    cv.h[0] = __float2bfloat16((v.x - mu) * rstd * gv.x + bv.x);
    cv.h[1] = __float2bfloat16((v.y - mu) * rstd * gv.y + bv.y);
    cv.h[2] = __float2bfloat16((v.z - mu) * rstd * gv.z + bv.z);
    cv.h[3] = __float2bfloat16((v.w - mu) * rstd * gv.w + bv.w);
    ((ushort4*)xn)[row * 256 + tid] = cv.u;
}

// ------- bf16 MFMA GEMM, 128x128 tile, BK=64: A direct-from-global, B in LDS
// A-fragment (16 B/lane at A[row][kq*8]) is loaded straight from global and
// served by L1/L2 (block A working set 16 KB/iter fits L1); only B is staged
// in swizzled LDS. Halves LDS traffic vs both-staged (LDS-BW was the limiter).
template<bool BF16OUT>
__global__ __launch_bounds__(256) void gemm_bf16mm(
    const __hip_bfloat16* __restrict__ A,
    const __hip_bfloat16* __restrict__ W,
    void* __restrict__ Cv, int N, int K)
{
    __shared__ __hip_bfloat16 Bs[128 * 64];   // 16 KB
    int tid = threadIdx.x;
    int lane = tid & 63;
    int w = tid >> 6, wr = w >> 1, wc = w & 1;
    int row0 = blockIdx.y * 128, col0 = blockIdx.x * 128;

    int sr = tid >> 3, sc = tid & 7;
    int gc = sc ^ (sr & 7);
    const __hip_bfloat16* bg = W + (size_t)(col0 + sr) * K + gc * 8;
    char* lb_st = (char*)Bs + w * 1024;       // + j*4096 per round
    const size_t rs32 = (size_t)32 * K;

    floatx4 acc[4][4];
    #pragma unroll
    for (int i = 0; i < 4; ++i)
        #pragma unroll
        for (int j = 0; j < 4; ++j) acc[i][j] = (floatx4){0.f, 0.f, 0.f, 0.f};

    int m = lane & 15, kq = lane >> 4;
    int s0 = kq ^ (m & 7);
    int s1 = (4 + kq) ^ (m & 7);
    const char* lb0 = (const char*)Bs + (wc * 64 + m) * 128 + s0 * 16;
    const char* lb1 = (const char*)Bs + (wc * 64 + m) * 128 + s1 * 16;

    // A fragment base: rows (row0 + wr*64 + m + 16i), k-offset kq*8.
    const __hip_bfloat16* afp = A + (size_t)(row0 + wr * 64 + m) * K + kq * 8;

    for (int k0 = 0; k0 < K; k0 += 64) {
        #pragma unroll
        for (int j = 0; j < 4; ++j)
            gld16(bg + j * rs32, lb_st + j * 4096);
        bg += 64;
        short8 a0f[4], a1f[4];
        #pragma unroll
        for (int i = 0; i < 4; ++i) {
            a0f[i] = *(const short8*)(afp + (size_t)i * 16 * K);
            a1f[i] = *(const short8*)(afp + (size_t)i * 16 * K + 32);
        }
        afp += 64;
        __syncthreads();                       // drains B staging + A loads
        {   // k-half 0
            short8 bf[4];
            #pragma unroll
            for (int j = 0; j < 4; ++j) bf[j] = *(const short8*)(lb0 + j * 2048);
            #pragma unroll
            for (int i = 0; i < 4; ++i)
                #pragma unroll
                for (int j = 0; j < 4; ++j)
                    acc[i][j] = __builtin_amdgcn_mfma_f32_16x16x32_bf16(
                        a0f[i], bf[j], acc[i][j], 0, 0, 0);
        }
        {   // k-half 1
            short8 bf[4];
            #pragma unroll
            for (int j = 0; j < 4; ++j) bf[j] = *(const short8*)(lb1 + j * 2048);
            #pragma unroll
            for (int i = 0; i < 4; ++i)
                #pragma unroll
                for (int j = 0; j < 4; ++j)
                    acc[i][j] = __builtin_amdgcn_mfma_f32_16x16x32_bf16(
                        a1f[i], bf[j], acc[i][j], 0, 0, 0);
        }
        __syncthreads();
    }

    // C/D layout: col = lane&15 (n), row = (lane>>4)*4 + reg (m)
    int crow = row0 + wr * 64 + kq * 4;
    int ccol = col0 + wc * 64 + m;
    #pragma unroll
    for (int i = 0; i < 4; ++i)
        #pragma unroll
        for (int j = 0; j < 4; ++j)
            #pragma unroll
            for (int r2 = 0; r2 < 4; ++r2) {
                size_t rr = (size_t)(crow + i * 16 + r2);
                int cc = ccol + j * 16;
                if (BF16OUT)
                    ((__hip_bfloat16*)Cv)[rr * N + cc] = __float2bfloat16(acc[i][j][r2]);
                else
                    ((float*)Cv)[rr * N + cc] = acc[i][j][r2];
            }
}

// ---------------- dt_proj: bf16 MFMA, K=64 (single BK step) -----------------
__global__ __launch_bounds__(256) void dtproj_mfma(
    const __hip_bfloat16* __restrict__ A,    // dtx 4096 x 64
    const __hip_bfloat16* __restrict__ W,    // dtw 2048 x 64
    const float* __restrict__ bias,
    __hip_bfloat16* __restrict__ dlt)
{
    __shared__ __hip_bfloat16 As[128 * 64];   // 16 KB
    __shared__ __hip_bfloat16 Bs[128 * 64];   // 16 KB
    int tid = threadIdx.x;
    int lane = tid & 63;
    int w = tid >> 6, wr = w >> 1, wc = w & 1;
    int row0 = blockIdx.y * 128, col0 = blockIdx.x * 128;
    const int K = DTR;                        // 64

    int sr = tid >> 3, sc = tid & 7;
    int gc = sc ^ (sr & 7);
    const __hip_bfloat16* ag = A + (size_t)(row0 + sr) * K + gc * 8;
    const __hip_bfloat16* bg = W + (size_t)(col0 + sr) * K + gc * 8;
    char* la_st = (char*)As + w * 1024;
    char* lb_st = (char*)Bs + w * 1024;
    const size_t rs32 = (size_t)32 * K;

    #pragma unroll
    for (int j = 0; j < 4; ++j) {
        gld16(ag + j * rs32, la_st + j * 4096);
        gld16(bg + j * rs32, lb_st + j * 4096);
    }

    floatx4 acc[4][4];
    #pragma unroll
    for (int i = 0; i < 4; ++i)
        #pragma unroll
        for (int j = 0; j < 4; ++j) acc[i][j] = (floatx4){0.f, 0.f, 0.f, 0.f};

    int m = lane & 15, kq = lane >> 4;
    int s0 = kq ^ (m & 7);
    int s1 = (4 + kq) ^ (m & 7);
    const char* la0 = (const char*)As + (wr * 64 + m) * 128 + s0 * 16;
    const char* la1 = (const char*)As + (wr * 64 + m) * 128 + s1 * 16;
    const char* lb0 = (const char*)Bs + (wc * 64 + m) * 128 + s0 * 16;
    const char* lb1 = (const char*)Bs + (wc * 64 + m) * 128 + s1 * 16;
    __syncthreads();
    {
        short8 af[4], bf[4];
        #pragma unroll
        for (int i = 0; i < 4; ++i) {
            af[i] = *(const short8*)(la0 + i * 2048);
            bf[i] = *(const short8*)(lb0 + i * 2048);
        }
        #pragma unroll
        for (int i = 0; i < 4; ++i)
            #pragma unroll
            for (int j = 0; j < 4; ++j)
                acc[i][j] = __builtin_amdgcn_mfma_f32_16x16x32_bf16(
                    af[i], bf[j], acc[i][j], 0, 0, 0);
    }
    {
        short8 af[4], bf[4];
        #pragma unroll
        for (int i = 0; i < 4; ++i) {
            af[i] = *(const short8*)(la1 + i * 2048);
            bf[i] = *(const short8*)(lb1 + i * 2048);
        }
        #pragma unroll
        for (int i = 0; i < 4; ++i)
            #pragma unroll
            for (int j = 0; j < 4; ++j)
                acc[i][j] = __builtin_amdgcn_mfma_f32_16x16x32_bf16(
                    af[i], bf[j], acc[i][j], 0, 0, 0);
    }

    int crow = row0 + wr * 64 + kq * 4;
    int ccol = col0 + wc * 64 + m;
    float bj[4];
    #pragma unroll
    for (int j = 0; j < 4; ++j) bj[j] = bias[ccol + j * 16];
    #pragma unroll
    for (int i = 0; i < 4; ++i)
        #pragma unroll
        for (int j = 0; j < 4; ++j)
            #pragma unroll
            for (int r2 = 0; r2 < 4; ++r2) {
                size_t rr = (size_t)(crow + i * 16 + r2);
                int cc = ccol + j * 16;
                dlt[rr * DI + cc] =
                    __float2bfloat16(softplus_fast(acc[i][j][r2] + bj[j]));
            }
}

// ------- bf16 MFMA GEMM, 64x128 tile, BK=64: A direct, B in LDS, +resid -----
__global__ __launch_bounds__(256) void gemm_bf16_n128(
    const __hip_bfloat16* __restrict__ A,
    const __hip_bfloat16* __restrict__ W,
    const float* __restrict__ resid,
    float* __restrict__ C, int N, int K)
{
    __shared__ __hip_bfloat16 Bs[128 * 64];   // 16 KB
    int tid = threadIdx.x;
    int lane = tid & 63;
    int w = tid >> 6;
    int row0 = blockIdx.y * 64, col0 = blockIdx.x * 128;

    int sr = tid >> 3, sc = tid & 7;
    int gc = sc ^ (sr & 7);
    const __hip_bfloat16* bg = W + (size_t)(col0 + sr) * K + gc * 8;
    char* lb_st = (char*)Bs + w * 1024;
    const size_t rs32 = (size_t)32 * K;

    floatx4 acc[4][2];
    #pragma unroll
    for (int i = 0; i < 4; ++i)
        #pragma unroll
        for (int j = 0; j < 2; ++j) acc[i][j] = (floatx4){0.f, 0.f, 0.f, 0.f};

    int m = lane & 15, kq = lane >> 4;
    int s0 = kq ^ (m & 7);
    int s1 = (4 + kq) ^ (m & 7);
    const char* lb0 = (const char*)Bs + (w * 32 + m) * 128 + s0 * 16;
    const char* lb1 = (const char*)Bs + (w * 32 + m) * 128 + s1 * 16;

    const __hip_bfloat16* afp = A + (size_t)(row0 + m) * K + kq * 8;

    for (int k0 = 0; k0 < K; k0 += 64) {
        #pragma unroll
        for (int j = 0; j < 4; ++j)
            gld16(bg + j * rs32, lb_st + j * 4096);
        bg += 64;
        short8 a0f[4], a1f[4];
        #pragma unroll
        for (int i = 0; i < 4; ++i) {
            a0f[i] = *(const short8*)(afp + (size_t)i * 16 * K);
            a1f[i] = *(const short8*)(afp + (size_t)i * 16 * K + 32);
        }
        afp += 64;
        __syncthreads();
        {
            short8 bf[2];
            #pragma unroll
            for (int j = 0; j < 2; ++j) bf[j] = *(const short8*)(lb0 + j * 2048);
            #pragma unroll
            for (int i = 0; i < 4; ++i)
                #pragma unroll
                for (int j = 0; j < 2; ++j)
                    acc[i][j] = __builtin_amdgcn_mfma_f32_16x16x32_bf16(
                        a0f[i], bf[j], acc[i][j], 0, 0, 0);
        }
        {
            short8 bf[2];
            #pragma unroll
            for (int j = 0; j < 2; ++j) bf[j] = *(const short8*)(lb1 + j * 2048);
            #pragma unroll
            for (int i = 0; i < 4; ++i)
                #pragma unroll
                for (int j = 0; j < 2; ++j)
                    acc[i][j] = __builtin_amdgcn_mfma_f32_16x16x32_bf16(
                        a1f[i], bf[j], acc[i][j], 0, 0, 0);
        }
        __syncthreads();
    }

    int crow = row0 + kq * 4;
    int ccol = col0 + w * 32 + m;
    #pragma unroll
    for (int i = 0; i < 4; ++i)
        #pragma unroll
        for (int j = 0; j < 2; ++j)
            #pragma unroll
            for (int r2 = 0; r2 < 4; ++r2) {
                size_t rr = (size_t)(crow + i * 16 + r2);
                int cc = ccol + j * 16;
                C[rr * N + cc] = acc[i][j][r2] + resid[rr * N + cc];
            }
}

// ---------------- x_proj: bf16 MFMA, N=96, register-only (no LDS) ----------
__global__ __launch_bounds__(256) void xproj_kernel(
    const __hip_bfloat16* __restrict__ A,    // 4096 x 2048
    const __hip_bfloat16* __restrict__ W,    // 96 x 2048
    float* __restrict__ xpart)
{
    int tid = threadIdx.x;
    int lane = tid & 63;
    int w = tid >> 6;
    int kz = blockIdx.y;
    int row0 = blockIdx.x * 128 + w * 32;
    int m  = lane & 15;
    int kq = lane >> 4;                      // 0..3

    floatx4 acc[2][6];
    #pragma unroll
    for (int i = 0; i < 2; ++i)
        #pragma unroll
        for (int j = 0; j < 6; ++j) acc[i][j] = (floatx4){0.f, 0.f, 0.f, 0.f};

    const __hip_bfloat16* a0 = A + (size_t)(row0 + m) * DI + kz * (DI / SKX) + kq * 8;
    const __hip_bfloat16* b0 = W + (size_t)m * DI + kz * (DI / SKX) + kq * 8;

    #pragma unroll
    for (int ks = 0; ks < (DI / SKX) / 32; ++ks) {   // 8 steps of BK=32
        short8 af0 = *(const short8*)(a0);
        short8 af1 = *(const short8*)(a0 + (size_t)16 * DI);
        #pragma unroll
        for (int j = 0; j < 6; ++j) {
            short8 bf = *(const short8*)(b0 + (size_t)j * 16 * DI);
            acc[0][j] = __builtin_amdgcn_mfma_f32_16x16x32_bf16(af0, bf, acc[0][j], 0, 0, 0);
            acc[1][j] = __builtin_amdgcn_mfma_f32_16x16x32_bf16(af1, bf, acc[1][j], 0, 0, 0);
        }
        a0 += 32; b0 += 32;
    }

    float* cp = xpart + (size_t)kz * XPROJ_PART;
    int crow = row0 + kq * 4;
    #pragma unroll
    for (int i = 0; i < 2; ++i)
        #pragma unroll
        for (int j = 0; j < 6; ++j)
            #pragma unroll
            for (int r = 0; r < 4; ++r)
                cp[(size_t)(crow + i * 16 + r) * XDW + j * 16 + m] = acc[i][j][r];
}

// Reduce SKX partials into xdbl (fp32); also emit bf16 dt-columns for dtproj.
__global__ __launch_bounds__(256) void reduce8_kernel(
    const float* __restrict__ part, float* __restrict__ xdbl,
    __hip_bfloat16* __restrict__ dtx)
{
    int i = blockIdx.x * 256 + threadIdx.x;    // over 4096*96
    float s = 0.f;
    #pragma unroll
    for (int k = 0; k < SKX; ++k) s += part[(size_t)k * XPROJ_PART + i];
    xdbl[i] = s;
    int row = i / XDW;
    int col = i - row * XDW;
    if (col < DTR)
        dtx[(size_t)row * DTR + col] = __float2bfloat16(s);
}

// ---------------- Causal depthwise conv (width 4) + SiLU, bf16 in/out -------
__global__ __launch_bounds__(256) void conv_silu_kernel(
    const __hip_bfloat16* __restrict__ xz, const float* __restrict__ cw,
    const float* __restrict__ cb, ushort4* __restrict__ uc_bf)
{
    int i4 = blockIdx.x * 256 + threadIdx.x;   // 4-ch group over NB*LSEQ*DI/4
    int d4 = i4 & 511;                          // DI/4 = 512
    int bt = i4 >> 9;
    int t  = bt & (LSEQ - 1);
    int d  = d4 * 4;
    float4 w0 = *(const float4*)(cw + (size_t)(d+0) * 4);
    float4 w1 = *(const float4*)(cw + (size_t)(d+1) * 4);
    float4 w2 = *(const float4*)(cw + (size_t)(d+2) * 4);
    float4 w3 = *(const float4*)(cw + (size_t)(d+3) * 4);
    const float* wt0 = (const float*)&w0;
    const float* wt1 = (const float*)&w1;
    const float* wt2 = (const float*)&w2;
    const float* wt3 = (const float*)&w3;
    float4 acc = *(const float4*)(cb + d);
    const __hip_bfloat16* base = xz + ((size_t)bt << 12) + d;   // row stride 4096
    #pragma unroll
    for (int k = 0; k < 4; ++k) {
        int tp = t - 3 + k;
        if (tp >= 0) {
            union { ushort4 u; __hip_bfloat16 h[4]; } raw;
            raw.u = *(const ushort4*)(base - ((size_t)(3 - k) << 12));
            acc.x = fmaf(wt0[k], __bfloat162float(raw.h[0]), acc.x);
            acc.y = fmaf(wt1[k], __bfloat162float(raw.h[1]), acc.y);
            acc.z = fmaf(wt2[k], __bfloat162float(raw.h[2]), acc.z);
            acc.w = fmaf(wt3[k], __bfloat162float(raw.h[3]), acc.w);
        }
    }
    union { __hip_bfloat16 h[4]; ushort4 u; } cv;
    cv.h[0] = __float2bfloat16(siluf(acc.x));
    cv.h[1] = __float2bfloat16(siluf(acc.y));
    cv.h[2] = __float2bfloat16(siluf(acc.z));
    cv.h[3] = __float2bfloat16(siluf(acc.w));
    uc_bf[i4] = cv.u;
}

// ---------------- Chunk-parallel selective scan (bf16 u / res / dlt) --------
template<bool FINAL>
__global__ __launch_bounds__(256) void scan_chunk_kernel(
    const __hip_bfloat16* __restrict__ dlt, const __hip_bfloat16* __restrict__ uc,
    const float* __restrict__ xdbl, const float* __restrict__ A_log,
    const float* __restrict__ Dp, const __hip_bfloat16* __restrict__ xz,
    float* __restrict__ P, float* __restrict__ S,
    __hip_bfloat16* __restrict__ y)
{
    __shared__ float sBC[TCH][32];     // [tt][0:16]=B, [16:32]=C
    int tid = threadIdx.x;
    int d = blockIdx.x * 256 + tid;
    int c = blockIdx.y;
    int b = blockIdx.z;
    int row0 = b * LSEQ + c * TCH;

    {   // stage B,C rows of this chunk
        int tt = tid >> 3, j4 = (tid & 7) * 4;
        const float4* src = (const float4*)(xdbl + (size_t)(row0 + tt) * XDW + DTR + j4);
        *(float4*)(&sBC[tt][j4]) = *src;
    }
    __syncthreads();

    float Ac[DS], h[DS], p[DS];
    #pragma unroll
    for (int s = 0; s < DS; ++s) {
        Ac[s] = -expf(A_log[(size_t)d * DS + s]);
        p[s] = 1.f;
    }
    size_t soff = (((size_t)b * CCH + c) * DI + d) * DS;
    if (FINAL) {
        #pragma unroll
        for (int s = 0; s < DS; ++s) h[s] = S[soff + s];   // H0 from pass B
    } else {
        #pragma unroll
        for (int s = 0; s < DS; ++s) h[s] = 0.f;
    }
    float Dd = Dp[d];
    size_t ix = (size_t)row0 * DI + d;
    for (int tt = 0; tt < TCH; ++tt) {
        float dv = __bfloat162float(dlt[ix]);
        float ut = __bfloat162float(uc[ix]);
        float du = dv * ut;
        float yacc = 0.f;
        #pragma unroll
        for (int s = 0; s < DS; ++s) {
            float e = __expf(dv * Ac[s]);
            h[s] = fmaf(e, h[s], du * sBC[tt][s]);
            if (FINAL) yacc = fmaf(h[s], sBC[tt][16 + s], yacc);
            else       p[s] *= e;
        }
        if (FINAL) {
            float res = __bfloat162float(xz[((size_t)(row0 + tt) << 12) + DI + d]);
            y[ix] = __float2bfloat16(fmaf(ut, Dd, yacc) * siluf(res));
        }
        ix += DI;
    }
    if (!FINAL) {
        #pragma unroll
        for (int s = 0; s < DS; ++s) { P[soff + s] = p[s]; S[soff + s] = h[s]; }
    }
}

// Pass B: per (b,d,s), sequentially combine chunks; S[c] becomes H0 of chunk c.
__global__ __launch_bounds__(256) void scan_combine_kernel(
    const float* __restrict__ P, float* __restrict__ S)
{
    int idx = blockIdx.x * 256 + threadIdx.x;   // over NB*DI*DS = 65536
    int b = idx >> 15;                          // DI*DS = 32768
    int rest = idx & 32767;
    float h = 0.f;
    for (int c = 0; c < CCH; ++c) {
        size_t off = (((size_t)b * CCH + c) << 15) + rest;
        float tmp = S[off];
        float pv  = P[off];
        S[off] = h;                             // chunk-start state
        h = fmaf(pv, h, tmp);                   // chunk-end state
    }
}

extern "C" void kernel_launch(void* const* d_in, const int* in_sizes, int n_in,
                              void* d_out, int out_size, void* d_ws, size_t ws_size,
                              hipStream_t stream)
{
    const float* x        = (const float*)d_in[0];
    const float* ln_g     = (const float*)d_in[1];
    const float* ln_b     = (const float*)d_in[2];
    const float* in_w     = (const float*)d_in[3];   // (4096, 1024)
    const float* conv_w   = (const float*)d_in[4];   // (2048, 1, 4)
    const float* conv_b   = (const float*)d_in[5];
    const float* xproj_w  = (const float*)d_in[6];   // (96, 2048)
    const float* dtproj_w = (const float*)d_in[7];   // (2048, 64)
    const float* dtproj_b = (const float*)d_in[8];
    const float* A_log    = (const float*)d_in[9];   // (2048, 16)
    const float* Dvec     = (const float*)d_in[10];
    const float* out_w    = (const float*)d_in[11];  // (1024, 2048)
    float* out = (float*)d_out;

    // Workspace layout (byte offsets). Total 157,941,760 B = 157.9 MB.
    char* base = (char*)d_ws;
    __hip_bfloat16* xz_bf    = (__hip_bfloat16*)(base + 0);           // 4096x4096
    __hip_bfloat16* dlt_bf   = (__hip_bfloat16*)(base + 33554432);    // 4096x2048 bf16
    __hip_bfloat16* uc_bf    = (__hip_bfloat16*)(base + 67108864);    // 4096x2048
    float*          xdbl     = (float*)         (base + 83886080);    // 4096x96
    float*          xpart    = (float*)         (base + 85458944);    // 8x4096x96
    float*          Pch      = (float*)         (base + 85458944);    // alias (xpart dead after reduce8)
    float*          Sch      = (float*)         (base + 102236160);   // 2x64x2048x16
    __hip_bfloat16* xnorm_bf = (__hip_bfloat16*)(base + 119013376);   // 4096x1024
    __hip_bfloat16* yb_bf    = (__hip_bfloat16*)(base + 127401984);   // 4096x2048
    __hip_bfloat16* inw_bf   = (__hip_bfloat16*)(base + 144179200);   // 4096x1024
    __hip_bfloat16* outw_bf  = (__hip_bfloat16*)(base + 152567808);   // 1024x2048
    __hip_bfloat16* xpw_bf   = (__hip_bfloat16*)(base + 156762112);   // 96x2048
    __hip_bfloat16* dtx_bf   = (__hip_bfloat16*)(base + 157155328);   // 4096x64
    __hip_bfloat16* dtw_bf   = (__hip_bfloat16*)(base + 157679616);   // 2048x64

    const int R = NB * LSEQ;                  // 4096 rows

    // 0+1. weight conversions + LayerNorm in one launch
    prep_kernel<<<LN_BLOCKS + F2BF_BLOCKS, 256, 0, stream>>>(
        x, ln_g, ln_b, xnorm_bf,
        in_w, (ushort4*)inw_bf, out_w, (ushort4*)outw_bf,
        xproj_w, (ushort4*)xpw_bf, dtproj_w, (ushort4*)dtw_bf);
    // 2. in_proj (bf16 MFMA, A-direct/B-LDS hybrid): xz = xnorm @ in_w^T, bf16 out
    gemm_bf16mm<true><<<dim3((2*DI)/128, R/128), 256, 0, stream>>>(
        xnorm_bf, inw_bf, (void*)xz_bf, 2*DI, NE);
    // 3. causal depthwise conv + SiLU -> uc_bf
    conv_silu_kernel<<<(R * DI / 4) / 256, 256, 0, stream>>>(
        xz_bf, conv_w, conv_b, (ushort4*)uc_bf);
    // 4. x_proj (bf16 MFMA, register-only, split-K) + one-pass reduce (+bf16 dtx)
    xproj_kernel<<<dim3(R/128, SKX), 256, 0, stream>>>(uc_bf, xpw_bf, xpart);
    reduce8_kernel<<<(R * XDW) / 256, 256, 0, stream>>>(xpart, xdbl, dtx_bf);
    // 5. dt_proj + softplus (bf16 MFMA, single K-step) -> dlt (bf16)
    dtproj_mfma<<<dim3(DI/128, R/128), 256, 0, stream>>>(
        dtx_bf, dtw_bf, dtproj_b, dlt_bf);
    // 6. chunk-parallel selective scan (gate fused, bf16 y) -> yb_bf
    dim3 gScan(DI / 256, CCH, NB);            // 8 x 64 x 2 = 1024 blocks
    scan_chunk_kernel<false><<<gScan, 256, 0, stream>>>(
        dlt_bf, uc_bf, xdbl, A_log, Dvec, xz_bf, Pch, Sch, yb_bf);
    scan_combine_kernel<<<(NB * DI * DS) / 256, 256, 0, stream>>>(Pch, Sch);
    scan_chunk_kernel<true><<<gScan, 256, 0, stream>>>(
        dlt_bf, uc_bf, xdbl, A_log, Dvec, xz_bf, Pch, Sch, yb_bf);
    // 7. out_proj (bf16 MFMA, 64x128 tile, A-direct/B-LDS) + residual
    gemm_bf16_n128<<<dim3(NE/128, R/64), 256, 0, stream>>>(
        yb_bf, outw_bf, x, out, NE, DI);
}

// Round 12
// 322.371 us; speedup vs baseline: 1.2081x; 1.2081x over previous
//
#include <hip/hip_runtime.h>
#include <hip/hip_bf16.h>
#include <math.h>

// Problem constants
#define NE    1024   // n_embd
#define DI    2048   // d_inner
#define LSEQ  2048   // L
#define NB    2      // batch
#define DS    16     // d_state
#define DTR   64     // dt_rank
#define XDW   96     // dt_rank + 2*d_state

#define CCH   32           // number of time chunks for the scan
#define TCH   (LSEQ/CCH)   // 64 timesteps per chunk

#define SKX   8            // split-K factor for x_proj
#define XPROJ_PART (4096*96)

typedef __attribute__((ext_vector_type(8))) short short8;   // 8 x bf16 (4 VGPRs)
typedef __attribute__((ext_vector_type(4))) float floatx4;  // MFMA accumulator

__device__ __forceinline__ float softplus_fast(float x) {
    return (x > 20.f) ? x : __logf(1.f + __expf(x));
}
__device__ __forceinline__ float siluf(float x) {
    return x / (1.f + __expf(-x));
}

__device__ __forceinline__ void gld16(const void* g, void* l) {
    __builtin_amdgcn_global_load_lds(
        (const __attribute__((address_space(1))) unsigned int*)g,
        (__attribute__((address_space(3))) unsigned int*)l, 16, 0, 0);
}

// ---------------- prep: LayerNorm (blocks 0..4095) + 4x f2bf (rest) ---------
#define F2BF_N1 (4096*1024/4)          // in_w groups
#define F2BF_N2 (2048*1024/4)          // out_w groups
#define F2BF_N3 (96*2048/4)            // xproj_w groups
#define F2BF_N4 (2048*64/4)            // dtproj_w groups
#define LN_BLOCKS 4096
#define F2BF_BLOCKS ((F2BF_N1 + F2BF_N2 + F2BF_N3 + F2BF_N4) / 256)

__global__ __launch_bounds__(256) void prep_kernel(
    const float* __restrict__ x, const float* __restrict__ g,
    const float* __restrict__ b, __hip_bfloat16* __restrict__ xn,
    const float* __restrict__ s1, ushort4* __restrict__ d1,
    const float* __restrict__ s2, ushort4* __restrict__ d2,
    const float* __restrict__ s3, ushort4* __restrict__ d3,
    const float* __restrict__ s4, ushort4* __restrict__ d4)
{
    int tid = threadIdx.x;
    if (blockIdx.x >= LN_BLOCKS) {
        int i = (blockIdx.x - LN_BLOCKS) * 256 + tid;
        const float* src; ushort4* dst; int j;
        if (i < F2BF_N1)                           { src = s1; dst = d1; j = i; }
        else if (i < F2BF_N1 + F2BF_N2)            { src = s2; dst = d2; j = i - F2BF_N1; }
        else if (i < F2BF_N1 + F2BF_N2 + F2BF_N3)  { src = s3; dst = d3; j = i - F2BF_N1 - F2BF_N2; }
        else                                       { src = s4; dst = d4; j = i - F2BF_N1 - F2BF_N2 - F2BF_N3; }
        float4 v = ((const float4*)src)[j];
        union { __hip_bfloat16 h[4]; ushort4 u; } cv;
        cv.h[0] = __float2bfloat16(v.x);
        cv.h[1] = __float2bfloat16(v.y);
        cv.h[2] = __float2bfloat16(v.z);
        cv.h[3] = __float2bfloat16(v.w);
        dst[j] = cv.u;
        return;
    }
    int row = blockIdx.x;
    const float4* xr = (const float4*)(x + (size_t)row * NE);
    float4 v = xr[tid];                       // 256 threads * 4 = 1024
    float s  = v.x + v.y + v.z + v.w;
    float sq = v.x*v.x + v.y*v.y + v.z*v.z + v.w*v.w;
    #pragma unroll
    for (int off = 32; off > 0; off >>= 1) {  // wave64 reduce
        s  += __shfl_down(s, off);
        sq += __shfl_down(sq, off);
    }
    __shared__ float ss[4], ssq[4];
    __shared__ float smu, srstd;
    int wv = tid >> 6, lane = tid & 63;
    if (lane == 0) { ss[wv] = s; ssq[wv] = sq; }
    __syncthreads();
    if (tid == 0) {
        float a = ss[0] + ss[1] + ss[2] + ss[3];
        float q = ssq[0] + ssq[1] + ssq[2] + ssq[3];
        float mu  = a * (1.f / NE);
        float var = q * (1.f / NE) - mu * mu;   // biased var, matches jnp.var
        smu = mu; srstd = rsqrtf(var + 1e-5f);
    }
    __syncthreads();
    float mu = smu, rstd = srstd;
    float4 gv = ((const float4*)g)[tid];
    float4 bv = ((const float4*)b)[tid];
    union { __hip_bfloat16 h[4]; ushort4 u; } cv;
    cv.h[0] = __float2bfloat16((v.x - mu) * rstd * gv.x + bv.x);
    cv.h[1] = __float2bfloat16((v.y - mu) * rstd * gv.y + bv.y);
    cv.h[2] = __float2bfloat16((v.z - mu) * rstd * gv.z + bv.z);
    cv.h[3] = __float2bfloat16((v.w - mu) * rstd * gv.w + bv.w);
    ((ushort4*)xn)[row * 256 + tid] = cv.u;
}

// ------- in_proj: bf16 MFMA, 128x256 tile, BK=64, both-staged swizzled LDS --
// 4 waves; wave (wr,wc) computes 64 rows x 128 cols (acc[4][8]).
// LDS As 16 KB + Bs 32 KB = 48 KB; __launch_bounds__(256,2) for VGPR headroom.
__global__ __launch_bounds__(256, 2) void gemm_bf16_in(
    const __hip_bfloat16* __restrict__ A,
    const __hip_bfloat16* __restrict__ W,
    __hip_bfloat16* __restrict__ C, int N, int K)
{
    __shared__ __hip_bfloat16 As[128 * 64];   // 16 KB
    __shared__ __hip_bfloat16 Bs[256 * 64];   // 32 KB
    int tid = threadIdx.x;
    int lane = tid & 63;
    int w = tid >> 6, wr = w >> 1, wc = w & 1;
    int row0 = blockIdx.y * 128, col0 = blockIdx.x * 256;

    int sr = tid >> 3, sc = tid & 7;
    int gc = sc ^ (sr & 7);
    const __hip_bfloat16* ag = A + (size_t)(row0 + sr) * K + gc * 8;
    const __hip_bfloat16* bg = W + (size_t)(col0 + sr) * K + gc * 8;
    char* la_st = (char*)As + w * 1024;       // + j*4096 per 32-row round
    char* lb_st = (char*)Bs + w * 1024;
    const size_t rs32 = (size_t)32 * K;

    floatx4 acc[4][8];
    #pragma unroll
    for (int i = 0; i < 4; ++i)
        #pragma unroll
        for (int j = 0; j < 8; ++j) acc[i][j] = (floatx4){0.f, 0.f, 0.f, 0.f};

    int m = lane & 15, kq = lane >> 4;
    int s0 = kq ^ (m & 7);
    int s1 = (4 + kq) ^ (m & 7);
    const char* la0 = (const char*)As + (wr * 64 + m) * 128 + s0 * 16;
    const char* la1 = (const char*)As + (wr * 64 + m) * 128 + s1 * 16;
    const char* lb0 = (const char*)Bs + (wc * 128 + m) * 128 + s0 * 16;
    const char* lb1 = (const char*)Bs + (wc * 128 + m) * 128 + s1 * 16;

    for (int k0 = 0; k0 < K; k0 += 64) {
        #pragma unroll
        for (int j = 0; j < 4; ++j)
            gld16(ag + j * rs32, la_st + j * 4096);
        #pragma unroll
        for (int j = 0; j < 8; ++j)
            gld16(bg + j * rs32, lb_st + j * 4096);
        ag += 64; bg += 64;
        __syncthreads();
        {   // k-half 0
            short8 af[4], bf[8];
            #pragma unroll
            for (int i = 0; i < 4; ++i) af[i] = *(const short8*)(la0 + i * 2048);
            #pragma unroll
            for (int j = 0; j < 8; ++j) bf[j] = *(const short8*)(lb0 + j * 2048);
            #pragma unroll
            for (int i = 0; i < 4; ++i)
                #pragma unroll
                for (int j = 0; j < 8; ++j)
                    acc[i][j] = __builtin_amdgcn_mfma_f32_16x16x32_bf16(
                        af[i], bf[j], acc[i][j], 0, 0, 0);
        }
        {   // k-half 1
            short8 af[4], bf[8];
            #pragma unroll
            for (int i = 0; i < 4; ++i) af[i] = *(const short8*)(la1 + i * 2048);
            #pragma unroll
            for (int j = 0; j < 8; ++j) bf[j] = *(const short8*)(lb1 + j * 2048);
            #pragma unroll
            for (int i = 0; i < 4; ++i)
                #pragma unroll
                for (int j = 0; j < 8; ++j)
                    acc[i][j] = __builtin_amdgcn_mfma_f32_16x16x32_bf16(
                        af[i], bf[j], acc[i][j], 0, 0, 0);
        }
        __syncthreads();
    }

    // C/D layout: col = lane&15 (n), row = (lane>>4)*4 + reg (m)
    int crow = row0 + wr * 64 + kq * 4;
    int ccol = col0 + wc * 128 + m;
    #pragma unroll
    for (int i = 0; i < 4; ++i)
        #pragma unroll
        for (int j = 0; j < 8; ++j)
            #pragma unroll
            for (int r2 = 0; r2 < 4; ++r2) {
                size_t rr = (size_t)(crow + i * 16 + r2);
                int cc = ccol + j * 16;
                C[rr * N + cc] = __float2bfloat16(acc[i][j][r2]);
            }
}

// ---------------- dt_proj: bf16 MFMA, K=64 (single BK step) -----------------
__global__ __launch_bounds__(256) void dtproj_mfma(
    const __hip_bfloat16* __restrict__ A,    // dtx 4096 x 64
    const __hip_bfloat16* __restrict__ W,    // dtw 2048 x 64
    const float* __restrict__ bias,
    __hip_bfloat16* __restrict__ dlt)
{
    __shared__ __hip_bfloat16 As[128 * 64];   // 16 KB
    __shared__ __hip_bfloat16 Bs[128 * 64];   // 16 KB
    int tid = threadIdx.x;
    int lane = tid & 63;
    int w = tid >> 6, wr = w >> 1, wc = w & 1;
    int row0 = blockIdx.y * 128, col0 = blockIdx.x * 128;
    const int K = DTR;                        // 64

    int sr = tid >> 3, sc = tid & 7;
    int gc = sc ^ (sr & 7);
    const __hip_bfloat16* ag = A + (size_t)(row0 + sr) * K + gc * 8;
    const __hip_bfloat16* bg = W + (size_t)(col0 + sr) * K + gc * 8;
    char* la_st = (char*)As + w * 1024;
    char* lb_st = (char*)Bs + w * 1024;
    const size_t rs32 = (size_t)32 * K;

    #pragma unroll
    for (int j = 0; j < 4; ++j) {
        gld16(ag + j * rs32, la_st + j * 4096);
        gld16(bg + j * rs32, lb_st + j * 4096);
    }

    floatx4 acc[4][4];
    #pragma unroll
    for (int i = 0; i < 4; ++i)
        #pragma unroll
        for (int j = 0; j < 4; ++j) acc[i][j] = (floatx4){0.f, 0.f, 0.f, 0.f};

    int m = lane & 15, kq = lane >> 4;
    int s0 = kq ^ (m & 7);
    int s1 = (4 + kq) ^ (m & 7);
    const char* la0 = (const char*)As + (wr * 64 + m) * 128 + s0 * 16;
    const char* la1 = (const char*)As + (wr * 64 + m) * 128 + s1 * 16;
    const char* lb0 = (const char*)Bs + (wc * 64 + m) * 128 + s0 * 16;
    const char* lb1 = (const char*)Bs + (wc * 64 + m) * 128 + s1 * 16;
    __syncthreads();
    {
        short8 af[4], bf[4];
        #pragma unroll
        for (int i = 0; i < 4; ++i) {
            af[i] = *(const short8*)(la0 + i * 2048);
            bf[i] = *(const short8*)(lb0 + i * 2048);
        }
        #pragma unroll
        for (int i = 0; i < 4; ++i)
            #pragma unroll
            for (int j = 0; j < 4; ++j)
                acc[i][j] = __builtin_amdgcn_mfma_f32_16x16x32_bf16(
                    af[i], bf[j], acc[i][j], 0, 0, 0);
    }
    {
        short8 af[4], bf[4];
        #pragma unroll
        for (int i = 0; i < 4; ++i) {
            af[i] = *(const short8*)(la1 + i * 2048);
            bf[i] = *(const short8*)(lb1 + i * 2048);
        }
        #pragma unroll
        for (int i = 0; i < 4; ++i)
            #pragma unroll
            for (int j = 0; j < 4; ++j)
                acc[i][j] = __builtin_amdgcn_mfma_f32_16x16x32_bf16(
                    af[i], bf[j], acc[i][j], 0, 0, 0);
    }

    int crow = row0 + wr * 64 + kq * 4;
    int ccol = col0 + wc * 64 + m;
    float bj[4];
    #pragma unroll
    for (int j = 0; j < 4; ++j) bj[j] = bias[ccol + j * 16];
    #pragma unroll
    for (int i = 0; i < 4; ++i)
        #pragma unroll
        for (int j = 0; j < 4; ++j)
            #pragma unroll
            for (int r2 = 0; r2 < 4; ++r2) {
                size_t rr = (size_t)(crow + i * 16 + r2);
                int cc = ccol + j * 16;
                dlt[rr * DI + cc] =
                    __float2bfloat16(softplus_fast(acc[i][j][r2] + bj[j]));
            }
}

// ---------------- bf16 MFMA GEMM, 64x128 tile, BK=64, fp32 out + resid ------
// out_proj (round-10 both-staged version). LDS 24 KB.
__global__ __launch_bounds__(256) void gemm_bf16_n128(
    const __hip_bfloat16* __restrict__ A,
    const __hip_bfloat16* __restrict__ W,
    const float* __restrict__ resid,
    float* __restrict__ C, int N, int K)
{
    __shared__ __hip_bfloat16 As[64 * 64];    // 8 KB
    __shared__ __hip_bfloat16 Bs[128 * 64];   // 16 KB
    int tid = threadIdx.x;
    int lane = tid & 63;
    int w = tid >> 6;
    int row0 = blockIdx.y * 64, col0 = blockIdx.x * 128;

    int sr = tid >> 3, sc = tid & 7;
    int gc = sc ^ (sr & 7);
    const __hip_bfloat16* ag = A + (size_t)(row0 + sr) * K + gc * 8;
    const __hip_bfloat16* bg = W + (size_t)(col0 + sr) * K + gc * 8;
    char* la_st = (char*)As + w * 1024;
    char* lb_st = (char*)Bs + w * 1024;
    const size_t rs32 = (size_t)32 * K;

    floatx4 acc[4][2];
    #pragma unroll
    for (int i = 0; i < 4; ++i)
        #pragma unroll
        for (int j = 0; j < 2; ++j) acc[i][j] = (floatx4){0.f, 0.f, 0.f, 0.f};

    int m = lane & 15, kq = lane >> 4;
    int s0 = kq ^ (m & 7);
    int s1 = (4 + kq) ^ (m & 7);
    const char* la0 = (const char*)As + m * 128 + s0 * 16;
    const char* la1 = (const char*)As + m * 128 + s1 * 16;
    const char* lb0 = (const char*)Bs + (w * 32 + m) * 128 + s0 * 16;
    const char* lb1 = (const char*)Bs + (w * 32 + m) * 128 + s1 * 16;

    for (int k0 = 0; k0 < K; k0 += 64) {
        gld16(ag,        la_st);              // A rows 0..31
        gld16(ag + rs32, la_st + 4096);       // A rows 32..63
        #pragma unroll
        for (int j = 0; j < 4; ++j)
            gld16(bg + j * rs32, lb_st + j * 4096);
        ag += 64; bg += 64;
        __syncthreads();
        {
            short8 af[4], bf[2];
            #pragma unroll
            for (int i = 0; i < 4; ++i) af[i] = *(const short8*)(la0 + i * 2048);
            #pragma unroll
            for (int j = 0; j < 2; ++j) bf[j] = *(const short8*)(lb0 + j * 2048);
            #pragma unroll
            for (int i = 0; i < 4; ++i)
                #pragma unroll
                for (int j = 0; j < 2; ++j)
                    acc[i][j] = __builtin_amdgcn_mfma_f32_16x16x32_bf16(
                        af[i], bf[j], acc[i][j], 0, 0, 0);
        }
        {
            short8 af[4], bf[2];
            #pragma unroll
            for (int i = 0; i < 4; ++i) af[i] = *(const short8*)(la1 + i * 2048);
            #pragma unroll
            for (int j = 0; j < 2; ++j) bf[j] = *(const short8*)(lb1 + j * 2048);
            #pragma unroll
            for (int i = 0; i < 4; ++i)
                #pragma unroll
                for (int j = 0; j < 2; ++j)
                    acc[i][j] = __builtin_amdgcn_mfma_f32_16x16x32_bf16(
                        af[i], bf[j], acc[i][j], 0, 0, 0);
        }
        __syncthreads();
    }

    int crow = row0 + kq * 4;
    int ccol = col0 + w * 32 + m;
    #pragma unroll
    for (int i = 0; i < 4; ++i)
        #pragma unroll
        for (int j = 0; j < 2; ++j)
            #pragma unroll
            for (int r2 = 0; r2 < 4; ++r2) {
                size_t rr = (size_t)(crow + i * 16 + r2);
                int cc = ccol + j * 16;
                C[rr * N + cc] = acc[i][j][r2] + resid[rr * N + cc];
            }
}

// ---------------- x_proj: bf16 MFMA, N=96, register-only (no LDS) ----------
__global__ __launch_bounds__(256) void xproj_kernel(
    const __hip_bfloat16* __restrict__ A,    // 4096 x 2048
    const __hip_bfloat16* __restrict__ W,    // 96 x 2048
    float* __restrict__ xpart)
{
    int tid = threadIdx.x;
    int lane = tid & 63;
    int w = tid >> 6;
    int kz = blockIdx.y;
    int row0 = blockIdx.x * 128 + w * 32;
    int m  = lane & 15;
    int kq = lane >> 4;                      // 0..3

    floatx4 acc[2][6];
    #pragma unroll
    for (int i = 0; i < 2; ++i)
        #pragma unroll
        for (int j = 0; j < 6; ++j) acc[i][j] = (floatx4){0.f, 0.f, 0.f, 0.f};

    const __hip_bfloat16* a0 = A + (size_t)(row0 + m) * DI + kz * (DI / SKX) + kq * 8;
    const __hip_bfloat16* b0 = W + (size_t)m * DI + kz * (DI / SKX) + kq * 8;

    #pragma unroll
    for (int ks = 0; ks < (DI / SKX) / 32; ++ks) {   // 8 steps of BK=32
        short8 af0 = *(const short8*)(a0);
        short8 af1 = *(const short8*)(a0 + (size_t)16 * DI);
        #pragma unroll
        for (int j = 0; j < 6; ++j) {
            short8 bf = *(const short8*)(b0 + (size_t)j * 16 * DI);
            acc[0][j] = __builtin_amdgcn_mfma_f32_16x16x32_bf16(af0, bf, acc[0][j], 0, 0, 0);
            acc[1][j] = __builtin_amdgcn_mfma_f32_16x16x32_bf16(af1, bf, acc[1][j], 0, 0, 0);
        }
        a0 += 32; b0 += 32;
    }

    float* cp = xpart + (size_t)kz * XPROJ_PART;
    int crow = row0 + kq * 4;
    #pragma unroll
    for (int i = 0; i < 2; ++i)
        #pragma unroll
        for (int j = 0; j < 6; ++j)
            #pragma unroll
            for (int r = 0; r < 4; ++r)
                cp[(size_t)(crow + i * 16 + r) * XDW + j * 16 + m] = acc[i][j][r];
}

// Reduce SKX partials into xdbl (fp32); also emit bf16 dt-columns for dtproj.
__global__ __launch_bounds__(256) void reduce8_kernel(
    const float* __restrict__ part, float* __restrict__ xdbl,
    __hip_bfloat16* __restrict__ dtx)
{
    int i = blockIdx.x * 256 + threadIdx.x;    // over 4096*96
    float s = 0.f;
    #pragma unroll
    for (int k = 0; k < SKX; ++k) s += part[(size_t)k * XPROJ_PART + i];
    xdbl[i] = s;
    int row = i / XDW;
    int col = i - row * XDW;
    if (col < DTR)
        dtx[(size_t)row * DTR + col] = __float2bfloat16(s);
}

// ---------------- Causal depthwise conv (width 4) + SiLU, bf16 in/out -------
__global__ __launch_bounds__(256) void conv_silu_kernel(
    const __hip_bfloat16* __restrict__ xz, const float* __restrict__ cw,
    const float* __restrict__ cb, ushort4* __restrict__ uc_bf)
{
    int i4 = blockIdx.x * 256 + threadIdx.x;   // 4-ch group over NB*LSEQ*DI/4
    int d4 = i4 & 511;                          // DI/4 = 512
    int bt = i4 >> 9;
    int t  = bt & (LSEQ - 1);
    int d  = d4 * 4;
    float4 w0 = *(const float4*)(cw + (size_t)(d+0) * 4);
    float4 w1 = *(const float4*)(cw + (size_t)(d+1) * 4);
    float4 w2 = *(const float4*)(cw + (size_t)(d+2) * 4);
    float4 w3 = *(const float4*)(cw + (size_t)(d+3) * 4);
    const float* wt0 = (const float*)&w0;
    const float* wt1 = (const float*)&w1;
    const float* wt2 = (const float*)&w2;
    const float* wt3 = (const float*)&w3;
    float4 acc = *(const float4*)(cb + d);
    const __hip_bfloat16* base = xz + ((size_t)bt << 12) + d;   // row stride 4096
    #pragma unroll
    for (int k = 0; k < 4; ++k) {
        int tp = t - 3 + k;
        if (tp >= 0) {
            union { ushort4 u; __hip_bfloat16 h[4]; } raw;
            raw.u = *(const ushort4*)(base - ((size_t)(3 - k) << 12));
            acc.x = fmaf(wt0[k], __bfloat162float(raw.h[0]), acc.x);
            acc.y = fmaf(wt1[k], __bfloat162float(raw.h[1]), acc.y);
            acc.z = fmaf(wt2[k], __bfloat162float(raw.h[2]), acc.z);
            acc.w = fmaf(wt3[k], __bfloat162float(raw.h[3]), acc.w);
        }
    }
    union { __hip_bfloat16 h[4]; ushort4 u; } cv;
    cv.h[0] = __float2bfloat16(siluf(acc.x));
    cv.h[1] = __float2bfloat16(siluf(acc.y));
    cv.h[2] = __float2bfloat16(siluf(acc.z));
    cv.h[3] = __float2bfloat16(siluf(acc.w));
    uc_bf[i4] = cv.u;
}

// ---------------- Chunk-parallel selective scan (bf16 u / res / dlt) --------
template<bool FINAL>
__global__ __launch_bounds__(256) void scan_chunk_kernel(
    const __hip_bfloat16* __restrict__ dlt, const __hip_bfloat16* __restrict__ uc,
    const float* __restrict__ xdbl, const float* __restrict__ A_log,
    const float* __restrict__ Dp, const __hip_bfloat16* __restrict__ xz,
    float* __restrict__ P, float* __restrict__ S,
    __hip_bfloat16* __restrict__ y)
{
    __shared__ float sBC[TCH][32];     // [tt][0:16]=B, [16:32]=C  (8 KB)
    int tid = threadIdx.x;
    int d = blockIdx.x * 256 + tid;
    int c = blockIdx.y;
    int b = blockIdx.z;
    int row0 = b * LSEQ + c * TCH;

    {   // stage B,C rows of this chunk: TCH*8 float4 = 512, 2 per thread
        #pragma unroll
        for (int it = 0; it < 2; ++it) {
            int li = it * 256 + tid;
            int tt = li >> 3, j4 = (li & 7) * 4;
            const float4* src = (const float4*)(xdbl + (size_t)(row0 + tt) * XDW + DTR + j4);
            *(float4*)(&sBC[tt][j4]) = *src;
        }
    }
    __syncthreads();

    float Ac[DS], h[DS], p[DS];
    #pragma unroll
    for (int s = 0; s < DS; ++s) {
        Ac[s] = -expf(A_log[(size_t)d * DS + s]);
        p[s] = 1.f;
    }
    size_t soff = (((size_t)b * CCH + c) * DI + d) * DS;
    if (FINAL) {
        #pragma unroll
        for (int s = 0; s < DS; ++s) h[s] = S[soff + s];   // H0 from pass B
    } else {
        #pragma unroll
        for (int s = 0; s < DS; ++s) h[s] = 0.f;
    }
    float Dd = Dp[d];
    size_t ix = (size_t)row0 * DI + d;
    for (int tt = 0; tt < TCH; ++tt) {
        float dv = __bfloat162float(dlt[ix]);
        float ut = __bfloat162float(uc[ix]);
        float du = dv * ut;
        float yacc = 0.f;
        #pragma unroll
        for (int s = 0; s < DS; ++s) {
            float e = __expf(dv * Ac[s]);
            h[s] = fmaf(e, h[s], du * sBC[tt][s]);
            if (FINAL) yacc = fmaf(h[s], sBC[tt][16 + s], yacc);
            else       p[s] *= e;
        }
        if (FINAL) {
            float res = __bfloat162float(xz[((size_t)(row0 + tt) << 12) + DI + d]);
            y[ix] = __float2bfloat16(fmaf(ut, Dd, yacc) * siluf(res));
        }
        ix += DI;
    }
    if (!FINAL) {
        #pragma unroll
        for (int s = 0; s < DS; ++s) { P[soff + s] = p[s]; S[soff + s] = h[s]; }
    }
}

// Pass B: per (b,d,s), sequentially combine chunks; S[c] becomes H0 of chunk c.
__global__ __launch_bounds__(256) void scan_combine_kernel(
    const float* __restrict__ P, float* __restrict__ S)
{
    int idx = blockIdx.x * 256 + threadIdx.x;   // over NB*DI*DS = 65536
    int b = idx >> 15;                          // DI*DS = 32768
    int rest = idx & 32767;
    float h = 0.f;
    for (int c = 0; c < CCH; ++c) {
        size_t off = (((size_t)b * CCH + c) << 15) + rest;
        float tmp = S[off];
        float pv  = P[off];
        S[off] = h;                             // chunk-start state
        h = fmaf(pv, h, tmp);                   // chunk-end state
    }
}

extern "C" void kernel_launch(void* const* d_in, const int* in_sizes, int n_in,
                              void* d_out, int out_size, void* d_ws, size_t ws_size,
                              hipStream_t stream)
{
    const float* x        = (const float*)d_in[0];
    const float* ln_g     = (const float*)d_in[1];
    const float* ln_b     = (const float*)d_in[2];
    const float* in_w     = (const float*)d_in[3];   // (4096, 1024)
    const float* conv_w   = (const float*)d_in[4];   // (2048, 1, 4)
    const float* conv_b   = (const float*)d_in[5];
    const float* xproj_w  = (const float*)d_in[6];   // (96, 2048)
    const float* dtproj_w = (const float*)d_in[7];   // (2048, 64)
    const float* dtproj_b = (const float*)d_in[8];
    const float* A_log    = (const float*)d_in[9];   // (2048, 16)
    const float* Dvec     = (const float*)d_in[10];
    const float* out_w    = (const float*)d_in[11];  // (1024, 2048)
    float* out = (float*)d_out;

    // Workspace layout (byte offsets). Total 157,941,760 B = 157.9 MB.
    char* base = (char*)d_ws;
    __hip_bfloat16* xz_bf    = (__hip_bfloat16*)(base + 0);           // 4096x4096
    __hip_bfloat16* dlt_bf   = (__hip_bfloat16*)(base + 33554432);    // 4096x2048 bf16
    __hip_bfloat16* uc_bf    = (__hip_bfloat16*)(base + 67108864);    // 4096x2048
    float*          xdbl     = (float*)         (base + 83886080);    // 4096x96
    float*          xpart    = (float*)         (base + 85458944);    // 8x4096x96
    float*          Pch      = (float*)         (base + 85458944);    // alias (xpart dead after reduce8); 8.4 MB
    float*          Sch      = (float*)         (base + 102236160);   // 2x32x2048x16 = 8.4 MB
    __hip_bfloat16* xnorm_bf = (__hip_bfloat16*)(base + 119013376);   // 4096x1024
    __hip_bfloat16* yb_bf    = (__hip_bfloat16*)(base + 127401984);   // 4096x2048
    __hip_bfloat16* inw_bf   = (__hip_bfloat16*)(base + 144179200);   // 4096x1024
    __hip_bfloat16* outw_bf  = (__hip_bfloat16*)(base + 152567808);   // 1024x2048
    __hip_bfloat16* xpw_bf   = (__hip_bfloat16*)(base + 156762112);   // 96x2048
    __hip_bfloat16* dtx_bf   = (__hip_bfloat16*)(base + 157155328);   // 4096x64
    __hip_bfloat16* dtw_bf   = (__hip_bfloat16*)(base + 157679616);   // 2048x64

    const int R = NB * LSEQ;                  // 4096 rows

    // 0+1. weight conversions + LayerNorm in one launch
    prep_kernel<<<LN_BLOCKS + F2BF_BLOCKS, 256, 0, stream>>>(
        x, ln_g, ln_b, xnorm_bf,
        in_w, (ushort4*)inw_bf, out_w, (ushort4*)outw_bf,
        xproj_w, (ushort4*)xpw_bf, dtproj_w, (ushort4*)dtw_bf);
    // 2. in_proj (bf16 MFMA, 128x256 tile, both-staged): xz = xnorm @ in_w^T
    gemm_bf16_in<<<dim3((2*DI)/256, R/128), 256, 0, stream>>>(
        xnorm_bf, inw_bf, xz_bf, 2*DI, NE);
    // 3. causal depthwise conv + SiLU -> uc_bf
    conv_silu_kernel<<<(R * DI / 4) / 256, 256, 0, stream>>>(
        xz_bf, conv_w, conv_b, (ushort4*)uc_bf);
    // 4. x_proj (bf16 MFMA, register-only, split-K) + one-pass reduce (+bf16 dtx)
    xproj_kernel<<<dim3(R/128, SKX), 256, 0, stream>>>(uc_bf, xpw_bf, xpart);
    reduce8_kernel<<<(R * XDW) / 256, 256, 0, stream>>>(xpart, xdbl, dtx_bf);
    // 5. dt_proj + softplus (bf16 MFMA, single K-step) -> dlt (bf16)
    dtproj_mfma<<<dim3(DI/128, R/128), 256, 0, stream>>>(
        dtx_bf, dtw_bf, dtproj_b, dlt_bf);
    // 6. chunk-parallel selective scan (gate fused, bf16 y) -> yb_bf
    dim3 gScan(DI / 256, CCH, NB);            // 8 x 32 x 2 = 512 blocks
    scan_chunk_kernel<false><<<gScan, 256, 0, stream>>>(
        dlt_bf, uc_bf, xdbl, A_log, Dvec, xz_bf, Pch, Sch, yb_bf);
    scan_combine_kernel<<<(NB * DI * DS) / 256, 256, 0, stream>>>(Pch, Sch);
    scan_chunk_kernel<true><<<gScan, 256, 0, stream>>>(
        dlt_bf, uc_bf, xdbl, A_log, Dvec, xz_bf, Pch, Sch, yb_bf);
    // 7. out_proj (bf16 MFMA, 64x128 tile, BK=64, both-staged) + residual
    gemm_bf16_n128<<<dim3(NE/128, R/64), 256, 0, stream>>>(
        yb_bf, outw_bf, x, out, NE, DI);
}

// Round 13
// 293.066 us; speedup vs baseline: 1.3289x; 1.1000x over previous
//
#include <hip/hip_runtime.h>
#include <hip/hip_bf16.h>
#include <math.h>

// Problem constants
#define NE    1024   // n_embd
#define DI    2048   // d_inner
#define LSEQ  2048   // L
#define NB    2      // batch
#define DS    16     // d_state
#define DTR   64     // dt_rank
#define XDW   96     // dt_rank + 2*d_state

#define CCH   64           // number of time chunks for the scan
#define TCH   (LSEQ/CCH)   // 32 timesteps per chunk

#define SKX   8            // split-K factor for x_proj
#define XPROJ_PART (4096*96)

typedef __attribute__((ext_vector_type(8))) short short8;   // 8 x bf16 (4 VGPRs)
typedef __attribute__((ext_vector_type(4))) float floatx4;  // MFMA accumulator

__device__ __forceinline__ float softplus_fast(float x) {
    return (x > 20.f) ? x : __logf(1.f + __expf(x));
}
__device__ __forceinline__ float siluf(float x) {
    return x / (1.f + __expf(-x));
}

__device__ __forceinline__ void gld16(const void* g, void* l) {
    __builtin_amdgcn_global_load_lds(
        (const __attribute__((address_space(1))) unsigned int*)g,
        (__attribute__((address_space(3))) unsigned int*)l, 16, 0, 0);
}

// ---------------- prep: LayerNorm (blocks 0..4095) + 4x f2bf (rest) ---------
#define F2BF_N1 (4096*1024/4)          // in_w groups
#define F2BF_N2 (2048*1024/4)          // out_w groups
#define F2BF_N3 (96*2048/4)            // xproj_w groups
#define F2BF_N4 (2048*64/4)            // dtproj_w groups
#define LN_BLOCKS 4096
#define F2BF_BLOCKS ((F2BF_N1 + F2BF_N2 + F2BF_N3 + F2BF_N4) / 256)

__global__ __launch_bounds__(256) void prep_kernel(
    const float* __restrict__ x, const float* __restrict__ g,
    const float* __restrict__ b, __hip_bfloat16* __restrict__ xn,
    const float* __restrict__ s1, ushort4* __restrict__ d1,
    const float* __restrict__ s2, ushort4* __restrict__ d2,
    const float* __restrict__ s3, ushort4* __restrict__ d3,
    const float* __restrict__ s4, ushort4* __restrict__ d4)
{
    int tid = threadIdx.x;
    if (blockIdx.x >= LN_BLOCKS) {
        int i = (blockIdx.x - LN_BLOCKS) * 256 + tid;
        const float* src; ushort4* dst; int j;
        if (i < F2BF_N1)                           { src = s1; dst = d1; j = i; }
        else if (i < F2BF_N1 + F2BF_N2)            { src = s2; dst = d2; j = i - F2BF_N1; }
        else if (i < F2BF_N1 + F2BF_N2 + F2BF_N3)  { src = s3; dst = d3; j = i - F2BF_N1 - F2BF_N2; }
        else                                       { src = s4; dst = d4; j = i - F2BF_N1 - F2BF_N2 - F2BF_N3; }
        float4 v = ((const float4*)src)[j];
        union { __hip_bfloat16 h[4]; ushort4 u; } cv;
        cv.h[0] = __float2bfloat16(v.x);
        cv.h[1] = __float2bfloat16(v.y);
        cv.h[2] = __float2bfloat16(v.z);
        cv.h[3] = __float2bfloat16(v.w);
        dst[j] = cv.u;
        return;
    }
    int row = blockIdx.x;
    const float4* xr = (const float4*)(x + (size_t)row * NE);
    float4 v = xr[tid];                       // 256 threads * 4 = 1024
    float s  = v.x + v.y + v.z + v.w;
    float sq = v.x*v.x + v.y*v.y + v.z*v.z + v.w*v.w;
    #pragma unroll
    for (int off = 32; off > 0; off >>= 1) {  // wave64 reduce
        s  += __shfl_down(s, off);
        sq += __shfl_down(sq, off);
    }
    __shared__ float ss[4], ssq[4];
    __shared__ float smu, srstd;
    int wv = tid >> 6, lane = tid & 63;
    if (lane == 0) { ss[wv] = s; ssq[wv] = sq; }
    __syncthreads();
    if (tid == 0) {
        float a = ss[0] + ss[1] + ss[2] + ss[3];
        float q = ssq[0] + ssq[1] + ssq[2] + ssq[3];
        float mu  = a * (1.f / NE);
        float var = q * (1.f / NE) - mu * mu;   // biased var, matches jnp.var
        smu = mu; srstd = rsqrtf(var + 1e-5f);
    }
    __syncthreads();
    float mu = smu, rstd = srstd;
    float4 gv = ((const float4*)g)[tid];
    float4 bv = ((const float4*)b)[tid];
    union { __hip_bfloat16 h[4]; ushort4 u; } cv;
    cv.h[0] = __float2bfloat16((v.x - mu) * rstd * gv.x + bv.x);
    cv.h[1] = __float2bfloat16((v.y - mu) * rstd * gv.y + bv.y);
    cv.h[2] = __float2bfloat16((v.z - mu) * rstd * gv.z + bv.z);
    cv.h[3] = __float2bfloat16((v.w - mu) * rstd * gv.w + bv.w);
    ((ushort4*)xn)[row * 256 + tid] = cv.u;
}

// ------- in_proj: bf16 MFMA, 128x256 tile, BK=64, both-staged swizzled LDS --
__global__ __launch_bounds__(256, 2) void gemm_bf16_in(
    const __hip_bfloat16* __restrict__ A,
    const __hip_bfloat16* __restrict__ W,
    __hip_bfloat16* __restrict__ C, int N, int K)
{
    __shared__ __hip_bfloat16 As[128 * 64];   // 16 KB
    __shared__ __hip_bfloat16 Bs[256 * 64];   // 32 KB
    int tid = threadIdx.x;
    int lane = tid & 63;
    int w = tid >> 6, wr = w >> 1, wc = w & 1;
    int row0 = blockIdx.y * 128, col0 = blockIdx.x * 256;

    int sr = tid >> 3, sc = tid & 7;
    int gc = sc ^ (sr & 7);
    const __hip_bfloat16* ag = A + (size_t)(row0 + sr) * K + gc * 8;
    const __hip_bfloat16* bg = W + (size_t)(col0 + sr) * K + gc * 8;
    char* la_st = (char*)As + w * 1024;       // + j*4096 per 32-row round
    char* lb_st = (char*)Bs + w * 1024;
    const size_t rs32 = (size_t)32 * K;

    floatx4 acc[4][8];
    #pragma unroll
    for (int i = 0; i < 4; ++i)
        #pragma unroll
        for (int j = 0; j < 8; ++j) acc[i][j] = (floatx4){0.f, 0.f, 0.f, 0.f};

    int m = lane & 15, kq = lane >> 4;
    int s0 = kq ^ (m & 7);
    int s1 = (4 + kq) ^ (m & 7);
    const char* la0 = (const char*)As + (wr * 64 + m) * 128 + s0 * 16;
    const char* la1 = (const char*)As + (wr * 64 + m) * 128 + s1 * 16;
    const char* lb0 = (const char*)Bs + (wc * 128 + m) * 128 + s0 * 16;
    const char* lb1 = (const char*)Bs + (wc * 128 + m) * 128 + s1 * 16;

    for (int k0 = 0; k0 < K; k0 += 64) {
        #pragma unroll
        for (int j = 0; j < 4; ++j)
            gld16(ag + j * rs32, la_st + j * 4096);
        #pragma unroll
        for (int j = 0; j < 8; ++j)
            gld16(bg + j * rs32, lb_st + j * 4096);
        ag += 64; bg += 64;
        __syncthreads();
        {   // k-half 0
            short8 af[4], bf[8];
            #pragma unroll
            for (int i = 0; i < 4; ++i) af[i] = *(const short8*)(la0 + i * 2048);
            #pragma unroll
            for (int j = 0; j < 8; ++j) bf[j] = *(const short8*)(lb0 + j * 2048);
            #pragma unroll
            for (int i = 0; i < 4; ++i)
                #pragma unroll
                for (int j = 0; j < 8; ++j)
                    acc[i][j] = __builtin_amdgcn_mfma_f32_16x16x32_bf16(
                        af[i], bf[j], acc[i][j], 0, 0, 0);
        }
        {   // k-half 1
            short8 af[4], bf[8];
            #pragma unroll
            for (int i = 0; i < 4; ++i) af[i] = *(const short8*)(la1 + i * 2048);
            #pragma unroll
            for (int j = 0; j < 8; ++j) bf[j] = *(const short8*)(lb1 + j * 2048);
            #pragma unroll
            for (int i = 0; i < 4; ++i)
                #pragma unroll
                for (int j = 0; j < 8; ++j)
                    acc[i][j] = __builtin_amdgcn_mfma_f32_16x16x32_bf16(
                        af[i], bf[j], acc[i][j], 0, 0, 0);
        }
        __syncthreads();
    }

    int crow = row0 + wr * 64 + kq * 4;
    int ccol = col0 + wc * 128 + m;
    #pragma unroll
    for (int i = 0; i < 4; ++i)
        #pragma unroll
        for (int j = 0; j < 8; ++j)
            #pragma unroll
            for (int r2 = 0; r2 < 4; ++r2) {
                size_t rr = (size_t)(crow + i * 16 + r2);
                int cc = ccol + j * 16;
                C[rr * N + cc] = __float2bfloat16(acc[i][j][r2]);
            }
}

// ---------------- dt_proj: bf16 MFMA, K=64 (single BK step) -----------------
__global__ __launch_bounds__(256) void dtproj_mfma(
    const __hip_bfloat16* __restrict__ A,    // dtx 4096 x 64
    const __hip_bfloat16* __restrict__ W,    // dtw 2048 x 64
    const float* __restrict__ bias,
    __hip_bfloat16* __restrict__ dlt)
{
    __shared__ __hip_bfloat16 As[128 * 64];   // 16 KB
    __shared__ __hip_bfloat16 Bs[128 * 64];   // 16 KB
    int tid = threadIdx.x;
    int lane = tid & 63;
    int w = tid >> 6, wr = w >> 1, wc = w & 1;
    int row0 = blockIdx.y * 128, col0 = blockIdx.x * 128;
    const int K = DTR;                        // 64

    int sr = tid >> 3, sc = tid & 7;
    int gc = sc ^ (sr & 7);
    const __hip_bfloat16* ag = A + (size_t)(row0 + sr) * K + gc * 8;
    const __hip_bfloat16* bg = W + (size_t)(col0 + sr) * K + gc * 8;
    char* la_st = (char*)As + w * 1024;
    char* lb_st = (char*)Bs + w * 1024;
    const size_t rs32 = (size_t)32 * K;

    #pragma unroll
    for (int j = 0; j < 4; ++j) {
        gld16(ag + j * rs32, la_st + j * 4096);
        gld16(bg + j * rs32, lb_st + j * 4096);
    }

    floatx4 acc[4][4];
    #pragma unroll
    for (int i = 0; i < 4; ++i)
        #pragma unroll
        for (int j = 0; j < 4; ++j) acc[i][j] = (floatx4){0.f, 0.f, 0.f, 0.f};

    int m = lane & 15, kq = lane >> 4;
    int s0 = kq ^ (m & 7);
    int s1 = (4 + kq) ^ (m & 7);
    const char* la0 = (const char*)As + (wr * 64 + m) * 128 + s0 * 16;
    const char* la1 = (const char*)As + (wr * 64 + m) * 128 + s1 * 16;
    const char* lb0 = (const char*)Bs + (wc * 64 + m) * 128 + s0 * 16;
    const char* lb1 = (const char*)Bs + (wc * 64 + m) * 128 + s1 * 16;
    __syncthreads();
    {
        short8 af[4], bf[4];
        #pragma unroll
        for (int i = 0; i < 4; ++i) {
            af[i] = *(const short8*)(la0 + i * 2048);
            bf[i] = *(const short8*)(lb0 + i * 2048);
        }
        #pragma unroll
        for (int i = 0; i < 4; ++i)
            #pragma unroll
            for (int j = 0; j < 4; ++j)
                acc[i][j] = __builtin_amdgcn_mfma_f32_16x16x32_bf16(
                    af[i], bf[j], acc[i][j], 0, 0, 0);
    }
    {
        short8 af[4], bf[4];
        #pragma unroll
        for (int i = 0; i < 4; ++i) {
            af[i] = *(const short8*)(la1 + i * 2048);
            bf[i] = *(const short8*)(lb1 + i * 2048);
        }
        #pragma unroll
        for (int i = 0; i < 4; ++i)
            #pragma unroll
            for (int j = 0; j < 4; ++j)
                acc[i][j] = __builtin_amdgcn_mfma_f32_16x16x32_bf16(
                    af[i], bf[j], acc[i][j], 0, 0, 0);
    }

    int crow = row0 + wr * 64 + kq * 4;
    int ccol = col0 + wc * 64 + m;
    float bj[4];
    #pragma unroll
    for (int j = 0; j < 4; ++j) bj[j] = bias[ccol + j * 16];
    #pragma unroll
    for (int i = 0; i < 4; ++i)
        #pragma unroll
        for (int j = 0; j < 4; ++j)
            #pragma unroll
            for (int r2 = 0; r2 < 4; ++r2) {
                size_t rr = (size_t)(crow + i * 16 + r2);
                int cc = ccol + j * 16;
                dlt[rr * DI + cc] =
                    __float2bfloat16(softplus_fast(acc[i][j][r2] + bj[j]));
            }
}

// ---------------- bf16 MFMA GEMM, 64x128 tile, BK=64, fp32 out + resid ------
__global__ __launch_bounds__(256) void gemm_bf16_n128(
    const __hip_bfloat16* __restrict__ A,
    const __hip_bfloat16* __restrict__ W,
    const float* __restrict__ resid,
    float* __restrict__ C, int N, int K)
{
    __shared__ __hip_bfloat16 As[64 * 64];    // 8 KB
    __shared__ __hip_bfloat16 Bs[128 * 64];   // 16 KB
    int tid = threadIdx.x;
    int lane = tid & 63;
    int w = tid >> 6;
    int row0 = blockIdx.y * 64, col0 = blockIdx.x * 128;

    int sr = tid >> 3, sc = tid & 7;
    int gc = sc ^ (sr & 7);
    const __hip_bfloat16* ag = A + (size_t)(row0 + sr) * K + gc * 8;
    const __hip_bfloat16* bg = W + (size_t)(col0 + sr) * K + gc * 8;
    char* la_st = (char*)As + w * 1024;
    char* lb_st = (char*)Bs + w * 1024;
    const size_t rs32 = (size_t)32 * K;

    floatx4 acc[4][2];
    #pragma unroll
    for (int i = 0; i < 4; ++i)
        #pragma unroll
        for (int j = 0; j < 2; ++j) acc[i][j] = (floatx4){0.f, 0.f, 0.f, 0.f};

    int m = lane & 15, kq = lane >> 4;
    int s0 = kq ^ (m & 7);
    int s1 = (4 + kq) ^ (m & 7);
    const char* la0 = (const char*)As + m * 128 + s0 * 16;
    const char* la1 = (const char*)As + m * 128 + s1 * 16;
    const char* lb0 = (const char*)Bs + (w * 32 + m) * 128 + s0 * 16;
    const char* lb1 = (const char*)Bs + (w * 32 + m) * 128 + s1 * 16;

    for (int k0 = 0; k0 < K; k0 += 64) {
        gld16(ag,        la_st);              // A rows 0..31
        gld16(ag + rs32, la_st + 4096);       // A rows 32..63
        #pragma unroll
        for (int j = 0; j < 4; ++j)
            gld16(bg + j * rs32, lb_st + j * 4096);
        ag += 64; bg += 64;
        __syncthreads();
        {
            short8 af[4], bf[2];
            #pragma unroll
            for (int i = 0; i < 4; ++i) af[i] = *(const short8*)(la0 + i * 2048);
            #pragma unroll
            for (int j = 0; j < 2; ++j) bf[j] = *(const short8*)(lb0 + j * 2048);
            #pragma unroll
            for (int i = 0; i < 4; ++i)
                #pragma unroll
                for (int j = 0; j < 2; ++j)
                    acc[i][j] = __builtin_amdgcn_mfma_f32_16x16x32_bf16(
                        af[i], bf[j], acc[i][j], 0, 0, 0);
        }
        {
            short8 af[4], bf[2];
            #pragma unroll
            for (int i = 0; i < 4; ++i) af[i] = *(const short8*)(la1 + i * 2048);
            #pragma unroll
            for (int j = 0; j < 2; ++j) bf[j] = *(const short8*)(lb1 + j * 2048);
            #pragma unroll
            for (int i = 0; i < 4; ++i)
                #pragma unroll
                for (int j = 0; j < 2; ++j)
                    acc[i][j] = __builtin_amdgcn_mfma_f32_16x16x32_bf16(
                        af[i], bf[j], acc[i][j], 0, 0, 0);
        }
        __syncthreads();
    }

    int crow = row0 + kq * 4;
    int ccol = col0 + w * 32 + m;
    #pragma unroll
    for (int i = 0; i < 4; ++i)
        #pragma unroll
        for (int j = 0; j < 2; ++j)
            #pragma unroll
            for (int r2 = 0; r2 < 4; ++r2) {
                size_t rr = (size_t)(crow + i * 16 + r2);
                int cc = ccol + j * 16;
                C[rr * N + cc] = acc[i][j][r2] + resid[rr * N + cc];
            }
}

// ---------------- x_proj: bf16 MFMA, N=96, register-only (no LDS) ----------
__global__ __launch_bounds__(256) void xproj_kernel(
    const __hip_bfloat16* __restrict__ A,    // 4096 x 2048
    const __hip_bfloat16* __restrict__ W,    // 96 x 2048
    float* __restrict__ xpart)
{
    int tid = threadIdx.x;
    int lane = tid & 63;
    int w = tid >> 6;
    int kz = blockIdx.y;
    int row0 = blockIdx.x * 128 + w * 32;
    int m  = lane & 15;
    int kq = lane >> 4;                      // 0..3

    floatx4 acc[2][6];
    #pragma unroll
    for (int i = 0; i < 2; ++i)
        #pragma unroll
        for (int j = 0; j < 6; ++j) acc[i][j] = (floatx4){0.f, 0.f, 0.f, 0.f};

    const __hip_bfloat16* a0 = A + (size_t)(row0 + m) * DI + kz * (DI / SKX) + kq * 8;
    const __hip_bfloat16* b0 = W + (size_t)m * DI + kz * (DI / SKX) + kq * 8;

    #pragma unroll
    for (int ks = 0; ks < (DI / SKX) / 32; ++ks) {   // 8 steps of BK=32
        short8 af0 = *(const short8*)(a0);
        short8 af1 = *(const short8*)(a0 + (size_t)16 * DI);
        #pragma unroll
        for (int j = 0; j < 6; ++j) {
            short8 bf = *(const short8*)(b0 + (size_t)j * 16 * DI);
            acc[0][j] = __builtin_amdgcn_mfma_f32_16x16x32_bf16(af0, bf, acc[0][j], 0, 0, 0);
            acc[1][j] = __builtin_amdgcn_mfma_f32_16x16x32_bf16(af1, bf, acc[1][j], 0, 0, 0);
        }
        a0 += 32; b0 += 32;
    }

    float* cp = xpart + (size_t)kz * XPROJ_PART;
    int crow = row0 + kq * 4;
    #pragma unroll
    for (int i = 0; i < 2; ++i)
        #pragma unroll
        for (int j = 0; j < 6; ++j)
            #pragma unroll
            for (int r = 0; r < 4; ++r)
                cp[(size_t)(crow + i * 16 + r) * XDW + j * 16 + m] = acc[i][j][r];
}

// Reduce SKX partials into xdbl (fp32); also emit bf16 dt-columns for dtproj.
__global__ __launch_bounds__(256) void reduce8_kernel(
    const float* __restrict__ part, float* __restrict__ xdbl,
    __hip_bfloat16* __restrict__ dtx)
{
    int i = blockIdx.x * 256 + threadIdx.x;    // over 4096*96
    float s = 0.f;
    #pragma unroll
    for (int k = 0; k < SKX; ++k) s += part[(size_t)k * XPROJ_PART + i];
    xdbl[i] = s;
    int row = i / XDW;
    int col = i - row * XDW;
    if (col < DTR)
        dtx[(size_t)row * DTR + col] = __float2bfloat16(s);
}

// ---------------- Causal depthwise conv (width 4) + SiLU, bf16 in/out -------
__global__ __launch_bounds__(256) void conv_silu_kernel(
    const __hip_bfloat16* __restrict__ xz, const float* __restrict__ cw,
    const float* __restrict__ cb, ushort4* __restrict__ uc_bf)
{
    int i4 = blockIdx.x * 256 + threadIdx.x;   // 4-ch group over NB*LSEQ*DI/4
    int d4 = i4 & 511;                          // DI/4 = 512
    int bt = i4 >> 9;
    int t  = bt & (LSEQ - 1);
    int d  = d4 * 4;
    float4 w0 = *(const float4*)(cw + (size_t)(d+0) * 4);
    float4 w1 = *(const float4*)(cw + (size_t)(d+1) * 4);
    float4 w2 = *(const float4*)(cw + (size_t)(d+2) * 4);
    float4 w3 = *(const float4*)(cw + (size_t)(d+3) * 4);
    const float* wt0 = (const float*)&w0;
    const float* wt1 = (const float*)&w1;
    const float* wt2 = (const float*)&w2;
    const float* wt3 = (const float*)&w3;
    float4 acc = *(const float4*)(cb + d);
    const __hip_bfloat16* base = xz + ((size_t)bt << 12) + d;   // row stride 4096
    #pragma unroll
    for (int k = 0; k < 4; ++k) {
        int tp = t - 3 + k;
        if (tp >= 0) {
            union { ushort4 u; __hip_bfloat16 h[4]; } raw;
            raw.u = *(const ushort4*)(base - ((size_t)(3 - k) << 12));
            acc.x = fmaf(wt0[k], __bfloat162float(raw.h[0]), acc.x);
            acc.y = fmaf(wt1[k], __bfloat162float(raw.h[1]), acc.y);
            acc.z = fmaf(wt2[k], __bfloat162float(raw.h[2]), acc.z);
            acc.w = fmaf(wt3[k], __bfloat162float(raw.h[3]), acc.w);
        }
    }
    union { __hip_bfloat16 h[4]; ushort4 u; } cv;
    cv.h[0] = __float2bfloat16(siluf(acc.x));
    cv.h[1] = __float2bfloat16(siluf(acc.y));
    cv.h[2] = __float2bfloat16(siluf(acc.z));
    cv.h[3] = __float2bfloat16(siluf(acc.w));
    uc_bf[i4] = cv.u;
}

// ---------------- Chunk-parallel selective scan (bf16 u / res / dlt) --------
// Fast path (runtime-verified): A[d][s] = (s+1)*A[d][0] (true for this model's
// A_log = log(arange(1,17))) -> dA[s] = e1^(s+1), e1 = exp(dv*Ac0):
// 1 exp + 15 muls/step instead of 16 exps; pass A tracks p1 = prod(e1) only.
template<bool FINAL>
__global__ __launch_bounds__(256) void scan_chunk_kernel(
    const __hip_bfloat16* __restrict__ dlt, const __hip_bfloat16* __restrict__ uc,
    const float* __restrict__ xdbl, const float* __restrict__ A_log,
    const float* __restrict__ Dp, const __hip_bfloat16* __restrict__ xz,
    float* __restrict__ P, float* __restrict__ S,
    __hip_bfloat16* __restrict__ y)
{
    __shared__ float sBC[TCH][32];     // [tt][0:16]=B, [16:32]=C
    int tid = threadIdx.x;
    int d = blockIdx.x * 256 + tid;
    int c = blockIdx.y;
    int b = blockIdx.z;
    int row0 = b * LSEQ + c * TCH;

    {   // stage B,C rows of this chunk
        int tt = tid >> 3, j4 = (tid & 7) * 4;
        const float4* src = (const float4*)(xdbl + (size_t)(row0 + tt) * XDW + DTR + j4);
        *(float4*)(&sBC[tt][j4]) = *src;
    }
    __syncthreads();

    float Ac[DS], h[DS], p[DS];
    #pragma unroll
    for (int s = 0; s < DS; ++s) {
        Ac[s] = -expf(A_log[(size_t)d * DS + s]);
        p[s] = 1.f;
    }
    float Ac0 = Ac[0];
    bool fast = true;
    #pragma unroll
    for (int s = 1; s < DS; ++s)
        fast = fast && (fabsf(Ac[s] - (float)(s + 1) * Ac0) <= 1e-3f * fabsf(Ac[s]));

    size_t soff = (((size_t)b * CCH + c) * DI + d) * DS;
    if (FINAL) {
        #pragma unroll
        for (int s = 0; s < DS; ++s) h[s] = S[soff + s];   // H0 from pass B
    } else {
        #pragma unroll
        for (int s = 0; s < DS; ++s) h[s] = 0.f;
    }
    float Dd = Dp[d];
    size_t ix = (size_t)row0 * DI + d;

    if (fast) {
        float p1 = 1.f;
        float dv = __bfloat162float(dlt[ix]);
        float ut = __bfloat162float(uc[ix]);
        for (int tt = 0; tt < TCH; ++tt) {
            float dv_n = 0.f, ut_n = 0.f;
            if (tt + 1 < TCH) {                 // prefetch next timestep
                dv_n = __bfloat162float(dlt[ix + DI]);
                ut_n = __bfloat162float(uc[ix + DI]);
            }
            float du = dv * ut;
            float e1 = __expf(dv * Ac0);
            float e = 1.f;
            float yacc = 0.f;
            #pragma unroll
            for (int s = 0; s < DS; ++s) {
                e *= e1;                        // e = e1^(s+1) = dA[s]
                h[s] = fmaf(e, h[s], du * sBC[tt][s]);
                if (FINAL) yacc = fmaf(h[s], sBC[tt][16 + s], yacc);
            }
            if (!FINAL) p1 *= e1;
            if (FINAL) {
                float res = __bfloat162float(xz[((size_t)(row0 + tt) << 12) + DI + d]);
                y[ix] = __float2bfloat16(fmaf(ut, Dd, yacc) * siluf(res));
            }
            ix += DI;
            dv = dv_n; ut = ut_n;
        }
        if (!FINAL) {
            float e = 1.f;
            #pragma unroll
            for (int s = 0; s < DS; ++s) { e *= p1; p[s] = e; }
        }
    } else {
        for (int tt = 0; tt < TCH; ++tt) {
            float dv = __bfloat162float(dlt[ix]);
            float ut = __bfloat162float(uc[ix]);
            float du = dv * ut;
            float yacc = 0.f;
            #pragma unroll
            for (int s = 0; s < DS; ++s) {
                float e = __expf(dv * Ac[s]);
                h[s] = fmaf(e, h[s], du * sBC[tt][s]);
                if (FINAL) yacc = fmaf(h[s], sBC[tt][16 + s], yacc);
                else       p[s] *= e;
            }
            if (FINAL) {
                float res = __bfloat162float(xz[((size_t)(row0 + tt) << 12) + DI + d]);
                y[ix] = __float2bfloat16(fmaf(ut, Dd, yacc) * siluf(res));
            }
            ix += DI;
        }
    }
    if (!FINAL) {
        #pragma unroll
        for (int s = 0; s < DS; ++s) { P[soff + s] = p[s]; S[soff + s] = h[s]; }
    }
}

// Pass B: per (b,d,s), sequentially combine chunks; S[c] becomes H0 of chunk c.
__global__ __launch_bounds__(256) void scan_combine_kernel(
    const float* __restrict__ P, float* __restrict__ S)
{
    int idx = blockIdx.x * 256 + threadIdx.x;   // over NB*DI*DS = 65536
    int b = idx >> 15;                          // DI*DS = 32768
    int rest = idx & 32767;
    float h = 0.f;
    for (int c = 0; c < CCH; ++c) {
        size_t off = (((size_t)b * CCH + c) << 15) + rest;
        float tmp = S[off];
        float pv  = P[off];
        S[off] = h;                             // chunk-start state
        h = fmaf(pv, h, tmp);                   // chunk-end state
    }
}

extern "C" void kernel_launch(void* const* d_in, const int* in_sizes, int n_in,
                              void* d_out, int out_size, void* d_ws, size_t ws_size,
                              hipStream_t stream)
{
    const float* x        = (const float*)d_in[0];
    const float* ln_g     = (const float*)d_in[1];
    const float* ln_b     = (const float*)d_in[2];
    const float* in_w     = (const float*)d_in[3];   // (4096, 1024)
    const float* conv_w   = (const float*)d_in[4];   // (2048, 1, 4)
    const float* conv_b   = (const float*)d_in[5];
    const float* xproj_w  = (const float*)d_in[6];   // (96, 2048)
    const float* dtproj_w = (const float*)d_in[7];   // (2048, 64)
    const float* dtproj_b = (const float*)d_in[8];
    const float* A_log    = (const float*)d_in[9];   // (2048, 16)
    const float* Dvec     = (const float*)d_in[10];
    const float* out_w    = (const float*)d_in[11];  // (1024, 2048)
    float* out = (float*)d_out;

    // Workspace layout (byte offsets). Total 157,941,760 B = 157.9 MB.
    char* base = (char*)d_ws;
    __hip_bfloat16* xz_bf    = (__hip_bfloat16*)(base + 0);           // 4096x4096
    __hip_bfloat16* dlt_bf   = (__hip_bfloat16*)(base + 33554432);    // 4096x2048 bf16
    __hip_bfloat16* uc_bf    = (__hip_bfloat16*)(base + 67108864);    // 4096x2048
    float*          xdbl     = (float*)         (base + 83886080);    // 4096x96
    float*          xpart    = (float*)         (base + 85458944);    // 8x4096x96
    float*          Pch      = (float*)         (base + 85458944);    // alias; 16.8 MB
    float*          Sch      = (float*)         (base + 102236160);   // 2x64x2048x16
    __hip_bfloat16* xnorm_bf = (__hip_bfloat16*)(base + 119013376);   // 4096x1024
    __hip_bfloat16* yb_bf    = (__hip_bfloat16*)(base + 127401984);   // 4096x2048
    __hip_bfloat16* inw_bf   = (__hip_bfloat16*)(base + 144179200);   // 4096x1024
    __hip_bfloat16* outw_bf  = (__hip_bfloat16*)(base + 152567808);   // 1024x2048
    __hip_bfloat16* xpw_bf   = (__hip_bfloat16*)(base + 156762112);   // 96x2048
    __hip_bfloat16* dtx_bf   = (__hip_bfloat16*)(base + 157155328);   // 4096x64
    __hip_bfloat16* dtw_bf   = (__hip_bfloat16*)(base + 157679616);   // 2048x64

    const int R = NB * LSEQ;                  // 4096 rows

    // 0+1. weight conversions + LayerNorm in one launch
    prep_kernel<<<LN_BLOCKS + F2BF_BLOCKS, 256, 0, stream>>>(
        x, ln_g, ln_b, xnorm_bf,
        in_w, (ushort4*)inw_bf, out_w, (ushort4*)outw_bf,
        xproj_w, (ushort4*)xpw_bf, dtproj_w, (ushort4*)dtw_bf);
    // 2. in_proj (bf16 MFMA, 128x256 tile, both-staged): xz = xnorm @ in_w^T
    gemm_bf16_in<<<dim3((2*DI)/256, R/128), 256, 0, stream>>>(
        xnorm_bf, inw_bf, xz_bf, 2*DI, NE);
    // 3. causal depthwise conv + SiLU -> uc_bf
    conv_silu_kernel<<<(R * DI / 4) / 256, 256, 0, stream>>>(
        xz_bf, conv_w, conv_b, (ushort4*)uc_bf);
    // 4. x_proj (bf16 MFMA, register-only, split-K) + one-pass reduce (+bf16 dtx)
    xproj_kernel<<<dim3(R/128, SKX), 256, 0, stream>>>(uc_bf, xpw_bf, xpart);
    reduce8_kernel<<<(R * XDW) / 256, 256, 0, stream>>>(xpart, xdbl, dtx_bf);
    // 5. dt_proj + softplus (bf16 MFMA, single K-step) -> dlt (bf16)
    dtproj_mfma<<<dim3(DI/128, R/128), 256, 0, stream>>>(
        dtx_bf, dtw_bf, dtproj_b, dlt_bf);
    // 6. chunk-parallel selective scan (gate fused, bf16 y) -> yb_bf
    dim3 gScan(DI / 256, CCH, NB);            // 8 x 64 x 2 = 1024 blocks
    scan_chunk_kernel<false><<<gScan, 256, 0, stream>>>(
        dlt_bf, uc_bf, xdbl, A_log, Dvec, xz_bf, Pch, Sch, yb_bf);
    scan_combine_kernel<<<(NB * DI * DS) / 256, 256, 0, stream>>>(Pch, Sch);
    scan_chunk_kernel<true><<<gScan, 256, 0, stream>>>(
        dlt_bf, uc_bf, xdbl, A_log, Dvec, xz_bf, Pch, Sch, yb_bf);
    // 7. out_proj (bf16 MFMA, 64x128 tile, BK=64, both-staged) + residual
    gemm_bf16_n128<<<dim3(NE/128, R/64), 256, 0, stream>>>(
        yb_bf, outw_bf, x, out, NE, DI);
}